// Round 1
// baseline (93.687 us; speedup 1.0000x reference)
//
#include <hip/hip_runtime.h>
#include <hip/hip_bf16.h>

// Attention: B=512, T=128, C=512, H=64.  out[b,t,h] f32.
// Strategy: one 4-wave block per batch element; bf16 MFMA 16x16x32 for
// QKV projection, QK^T and PV; fused causal softmax in registers.
// Prep kernel converts W (f32) -> bf16 into d_ws (needs 192 KB).

#define TT 128
#define CC 512
#define HH 64

typedef __attribute__((ext_vector_type(8))) short bf16x8;
typedef __attribute__((ext_vector_type(4))) short bf16x4;
typedef __attribute__((ext_vector_type(4))) float f32x4;

__device__ __forceinline__ ushort f2bf(float f) {
    union { float f; unsigned u; } v; v.f = f;
    unsigned r = v.u + 0x7fffu + ((v.u >> 16) & 1u);  // RNE
    return (ushort)(r >> 16);
}

// ---- prep: Wq,Wk,Wv [64][512] f32 -> ws as bf16 [3][64][512] ----
__global__ void wconv_kernel(const float* __restrict__ wq,
                             const float* __restrict__ wk,
                             const float* __restrict__ wv,
                             ushort* __restrict__ wbf) {
    int idx = blockIdx.x * 256 + threadIdx.x;      // 0..98303
    int w = idx >> 15;
    int rem = idx & 32767;
    const float* src = (w == 0) ? wq : ((w == 1) ? wk : wv);
    wbf[idx] = f2bf(src[rem]);
}

__launch_bounds__(256, 2)
__global__ void attn_kernel(const float* __restrict__ x,
                            const ushort* __restrict__ wbf,
                            float* __restrict__ out) {
    // LDS: 80 KB total -> 2 blocks/CU.
    // xs: X chunk [128][128] bf16, XOR-swizzled; reused as P in phase 3.
    __shared__ __align__(16) ushort xs[128 * 128];
    __shared__ __align__(16) ushort qs[128 * 64];
    __shared__ __align__(16) ushort ks[128 * 64];
    __shared__ __align__(16) ushort vst[64 * 128];   // V transposed [h][t]

    const int tid  = threadIdx.x;
    const int wave = tid >> 6;
    const int lane = tid & 63;
    const int lq   = lane >> 4;     // quarter 0..3
    const int lr   = lane & 15;
    const int b    = blockIdx.x;
    const int row0 = wave * 32;     // this wave owns output rows row0..row0+31

    const float* xb = x + (size_t)b * (TT * CC);

    const f32x4 fzero = {0.f, 0.f, 0.f, 0.f};

    // ---------------- Phase 1: Q,K,V = X @ W^T (N = 3*64 = 12 n-tiles) ----
    f32x4 acc[2][12];
    #pragma unroll
    for (int i = 0; i < 2; ++i)
        #pragma unroll
        for (int j = 0; j < 12; ++j) acc[i][j] = fzero;

    for (int ck = 0; ck < 4; ++ck) {            // C chunks of 128
        __syncthreads();
        // stage X chunk [128][128] f32 -> bf16, swizzled: elem = r*128 + (c ^ ((r&7)<<3))
        #pragma unroll
        for (int it = 0; it < 16; ++it) {
            int idx = it * 256 + tid;           // 0..4095 quads
            int r = idx >> 5;
            int c = (idx & 31) << 2;
            float4 v = *(const float4*)(xb + r * CC + ck * 128 + c);
            bf16x4 pk;
            pk[0] = (short)f2bf(v.x); pk[1] = (short)f2bf(v.y);
            pk[2] = (short)f2bf(v.z); pk[3] = (short)f2bf(v.w);
            *(bf16x4*)&xs[r * 128 + (c ^ ((r & 7) << 3))] = pk;
        }
        __syncthreads();

        #pragma unroll
        for (int kt = 0; kt < 4; ++kt) {        // K sub-steps of 32
            bf16x8 a[2];
            #pragma unroll
            for (int mt = 0; mt < 2; ++mt) {
                int r  = row0 + mt * 16 + lr;
                int cc = kt * 32 + lq * 8;
                a[mt] = *(const bf16x8*)&xs[r * 128 + (cc ^ ((r & 7) << 3))];
            }
            int cg = ck * 128 + kt * 32 + lq * 8;
            #pragma unroll
            for (int nt = 0; nt < 12; ++nt) {
                int w = nt >> 2;
                int h = ((nt & 3) << 4) + lr;
                bf16x8 bb = *(const bf16x8*)&wbf[(w << 15) + h * 512 + cg];
                acc[0][nt] = __builtin_amdgcn_mfma_f32_16x16x32_bf16(a[0], bb, acc[0][nt], 0, 0, 0);
                acc[1][nt] = __builtin_amdgcn_mfma_f32_16x16x32_bf16(a[1], bb, acc[1][nt], 0, 0, 0);
            }
        }
    }

    // write Q,K (swizzled [t][h]) and V transposed (swizzled [h][t]) to LDS
    #pragma unroll
    for (int mt = 0; mt < 2; ++mt) {
        #pragma unroll
        for (int nt = 0; nt < 12; ++nt) {
            #pragma unroll
            for (int j = 0; j < 4; ++j) {
                int t = row0 + mt * 16 + lq * 4 + j;
                int h = ((nt & 3) << 4) + lr;
                ushort v = f2bf(acc[mt][nt][j]);
                if (nt < 4)      qs[t * 64 + (h ^ ((t & 7) << 3))] = v;
                else if (nt < 8) ks[t * 64 + (h ^ ((t & 7) << 3))] = v;
                else             vst[h * 128 + (t ^ ((h & 7) << 3))] = v;
            }
        }
    }
    __syncthreads();

    // ---------------- Phase 2: S = Q K^T, scale, causal softmax ----------
    f32x4 s[2][8];
    #pragma unroll
    for (int i = 0; i < 2; ++i)
        #pragma unroll
        for (int j = 0; j < 8; ++j) s[i][j] = fzero;

    #pragma unroll
    for (int kt = 0; kt < 2; ++kt) {
        int h0 = kt * 32 + lq * 8;
        bf16x8 a[2];
        #pragma unroll
        for (int mt = 0; mt < 2; ++mt) {
            int t = row0 + mt * 16 + lr;
            a[mt] = *(const bf16x8*)&qs[t * 64 + (h0 ^ ((t & 7) << 3))];
        }
        #pragma unroll
        for (int nt = 0; nt < 8; ++nt) {
            int sc = nt * 16 + lr;
            bf16x8 bb = *(const bf16x8*)&ks[sc * 64 + (h0 ^ ((sc & 7) << 3))];
            s[0][nt] = __builtin_amdgcn_mfma_f32_16x16x32_bf16(a[0], bb, s[0][nt], 0, 0, 0);
            s[1][nt] = __builtin_amdgcn_mfma_f32_16x16x32_bf16(a[1], bb, s[1][nt], 0, 0, 0);
        }
    }

    float rinv[2][4];
    #pragma unroll
    for (int mt = 0; mt < 2; ++mt) {
        #pragma unroll
        for (int j = 0; j < 4; ++j) {
            int t = row0 + mt * 16 + lq * 4 + j;   // block-local row (0..127)
            float m = -1e30f;
            #pragma unroll
            for (int nt = 0; nt < 8; ++nt) {
                int sc = nt * 16 + lr;
                float v = s[mt][nt][j] * 0.125f;
                v = (sc <= t) ? v : -1e30f;        // causal mask
                s[mt][nt][j] = v;
                m = fmaxf(m, v);
            }
            m = fmaxf(m, __shfl_xor(m, 1));
            m = fmaxf(m, __shfl_xor(m, 2));
            m = fmaxf(m, __shfl_xor(m, 4));
            m = fmaxf(m, __shfl_xor(m, 8));
            float sum = 0.f;
            #pragma unroll
            for (int nt = 0; nt < 8; ++nt) {
                float p = __expf(s[mt][nt][j] - m);
                s[mt][nt][j] = p;
                sum += p;
            }
            sum += __shfl_xor(sum, 1);
            sum += __shfl_xor(sum, 2);
            sum += __shfl_xor(sum, 4);
            sum += __shfl_xor(sum, 8);
            rinv[mt][j] = 1.0f / sum;              // deferred normalization
            // P (unnormalized, <=1) -> bf16 -> xs (reused as P buffer)
            #pragma unroll
            for (int nt = 0; nt < 8; ++nt) {
                int sc = nt * 16 + lr;
                xs[t * 128 + (sc ^ ((t & 7) << 3))] = f2bf(s[mt][nt][j]);
            }
        }
    }
    __syncthreads();   // safety: P fully in LDS before PV reads

    // ---------------- Phase 3: O = P V ------------------------------------
    f32x4 o[2][4];
    #pragma unroll
    for (int i = 0; i < 2; ++i)
        #pragma unroll
        for (int j = 0; j < 4; ++j) o[i][j] = fzero;

    #pragma unroll
    for (int ksv = 0; ksv < 4; ++ksv) {
        int s0 = ksv * 32 + lq * 8;
        bf16x8 a[2];
        #pragma unroll
        for (int mt = 0; mt < 2; ++mt) {
            int t = row0 + mt * 16 + lr;
            a[mt] = *(const bf16x8*)&xs[t * 128 + (s0 ^ ((t & 7) << 3))];
        }
        #pragma unroll
        for (int nt = 0; nt < 4; ++nt) {
            int h = nt * 16 + lr;
            bf16x8 bb = *(const bf16x8*)&vst[h * 128 + (s0 ^ ((h & 7) << 3))];
            o[0][nt] = __builtin_amdgcn_mfma_f32_16x16x32_bf16(a[0], bb, o[0][nt], 0, 0, 0);
            o[1][nt] = __builtin_amdgcn_mfma_f32_16x16x32_bf16(a[1], bb, o[1][nt], 0, 0, 0);
        }
    }

    float* ob = out + (size_t)b * (TT * HH);
    #pragma unroll
    for (int mt = 0; mt < 2; ++mt)
        #pragma unroll
        for (int nt = 0; nt < 4; ++nt)
            #pragma unroll
            for (int j = 0; j < 4; ++j) {
                int t = row0 + mt * 16 + lq * 4 + j;
                int h = nt * 16 + lr;
                ob[t * HH + h] = o[mt][nt][j] * rinv[mt][j];
            }
}

extern "C" void kernel_launch(void* const* d_in, const int* in_sizes, int n_in,
                              void* d_out, int out_size, void* d_ws, size_t ws_size,
                              hipStream_t stream) {
    const float* x  = (const float*)d_in[0];
    const float* wq = (const float*)d_in[1];
    const float* wk = (const float*)d_in[2];
    const float* wv = (const float*)d_in[3];
    float* o = (float*)d_out;
    ushort* wbf = (ushort*)d_ws;    // needs 3*64*512*2 = 196608 bytes

    (void)in_sizes; (void)n_in; (void)out_size; (void)ws_size;

    wconv_kernel<<<384, 256, 0, stream>>>(wq, wk, wv, wbf);
    attn_kernel<<<512, 256, 0, stream>>>(x, wbf, o);
}